// Round 3
// baseline (1410.290 us; speedup 1.0000x reference)
//
#include <hip/hip_runtime.h>

// SemiseparableLayer on MI355X (gfx950). Dual-dtype (runtime-detected bf16 / fp32)
// chunked (16 x 32-stage) linear-scan decomposition, MFMA 16x16x32 bf16,
// hi/lo-compensated bf16 state (~17-bit effective mantissa across 512 stages).
//
// ws: [0]      int flag (0=bf16 inputs, 1=fp32 inputs), written by k_detect each launch
//     +1024B   Sc/xin [16][4128][32] fp32   (chunk sums + P^T rows; K2 overwrites with entry states)
//     +...     Sa/zin [16][4128][32] fp32
// total = 1024 + 16,908,288 bytes

#define BATCH 4096
#define NCH   16
#define CHS   32
#define SROWS (BATCH + 32)
#define TSTR  36

typedef __attribute__((ext_vector_type(8))) short short8;
typedef __attribute__((ext_vector_type(4))) float f32x4;
typedef short8 __attribute__((may_alias)) short8a;
typedef unsigned __attribute__((may_alias)) uinta;

#define MFMA16(a, b, c) __builtin_amdgcn_mfma_f32_16x16x32_bf16(a, b, c, 0, 0, 0)

__device__ __forceinline__ unsigned short bf16u(float x) {
  unsigned u = __builtin_bit_cast(unsigned, x);
  u += 0x7fffu + ((u >> 16) & 1u);
  return (unsigned short)(u >> 16);
}
__device__ __forceinline__ float bf2f(unsigned short u) {
  return __builtin_bit_cast(float, ((unsigned)u) << 16);
}
__device__ __forceinline__ unsigned pk2(float a, float b) {
  return (unsigned)bf16u(a) | (((unsigned)bf16u(b)) << 16);
}
template <int DT>
__device__ __forceinline__ const void* eptr(const void* b, long e) {
  return (const char*)b + e * (DT ? 4 : 2);
}

// stage matrix -> LDS hi(+lo) bf16 planes, padded stride PSTR (shorts)
template <int DT, int ROWS, int COLS, int PSTR>
__device__ __forceinline__ void stage2(const void* gp, short* hi, short* lo, int tid) {
  if constexpr (DT == 0) {
    const uinta* gu = (const uinta*)gp;
    for (int i = tid; i < ROWS * COLS / 2; i += 256) {
      int r = i / (COLS / 2), c = i - r * (COLS / 2);
      ((uinta*)(hi + r * PSTR))[c] = gu[i];
    }
  } else {
    const float* gf = (const float*)gp;
    for (int i = tid; i < ROWS * COLS; i += 256) {
      int r = i / COLS, c = i - r * COLS;
      float v = gf[i];
      unsigned short h = bf16u(v);
      hi[r * PSTR + c] = (short)h;
      lo[r * PSTR + c] = (short)bf16u(v - bf2f(h));
    }
  }
}
// hi-only variant (output matrices C, D, G)
template <int DT, int ROWS, int COLS, int PSTR>
__device__ __forceinline__ void stage1(const void* gp, short* hi, int tid) {
  if constexpr (DT == 0) {
    const uinta* gu = (const uinta*)gp;
    for (int i = tid; i < ROWS * COLS / 2; i += 256) {
      int r = i / (COLS / 2), c = i - r * (COLS / 2);
      ((uinta*)(hi + r * PSTR))[c] = gu[i];
    }
  } else {
    const float* gf = (const float*)gp;
    for (int i = tid; i < ROWS * COLS; i += 256) {
      int r = i / COLS, c = i - r * COLS;
      hi[r * PSTR + c] = (short)bf16u(gf[i]);
    }
  }
}

// B-operand fragment of 32-col matrix stored [n][k] stride 40: B[k][n] = M[n][k]
__device__ __forceinline__ short8 ldfrag32(const short* l, int lane, int nbase) {
  int n = nbase + (lane & 15), q = lane >> 4;
  return *(const short8a*)(l + n * 40 + q * 8);
}
// B-operand fragment of 16-col matrix stride 24; rows k>=16 zero
__device__ __forceinline__ short8 ldfrag16(const short* l, int lane, int nbase) {
  int n = nbase + (lane & 15), q = lane >> 4;
  short8 z = {};
  if (q < 2) z = *(const short8a*)(l + n * 24 + q * 8);
  return z;
}

// fp32 C-layout (col=lane&15,row=quad*4+r) -> fp32 plane [16][TSTR]
__device__ __forceinline__ void twr(const f32x4* acc, float* T, int lane) {
  const int c = lane & 15, q = lane >> 4;
#pragma unroll
  for (int h = 0; h < 2; ++h)
#pragma unroll
    for (int r = 0; r < 4; ++r) T[(q * 4 + r) * TSTR + h * 16 + c] = acc[h][r];
}
// plane -> A-frag (A[m=lane&15][k=quad*8+j]) with reader-side hi/lo split
__device__ __forceinline__ void trd(const float* T, int lane, short8& hi, short8& lo) {
  const int m = lane & 15, q = lane >> 4;
  const float* p = T + m * TSTR + q * 8;
#pragma unroll
  for (int j = 0; j < 8; ++j) {
    float v = p[j];
    unsigned short h = bf16u(v);
    hi[j] = (short)h;
    lo[j] = (short)bf16u(v - bf2f(h));
  }
}

// u-row fragment loader (element offset), hi/lo
template <int DT>
__device__ __forceinline__ void ldu(const void* U, size_t off, short8& uhi, short8& ulo) {
  if constexpr (DT == 0) {
    uhi = *(const short8a*)((const short*)U + off);
    ulo = short8{};
  } else {
    const float* p = (const float*)U + off;
#pragma unroll
    for (int j = 0; j < 8; ++j) {
      float v = p[j];
      unsigned short h = bf16u(v);
      uhi[j] = (short)h;
      ulo[j] = (short)bf16u(v - bf2f(h));
    }
  }
}
template <int DT>
__device__ __forceinline__ float ldbias(const void* b, int i) {
  if constexpr (DT == 0) return bf2f((unsigned short)((const short*)b)[i]);
  else return ((const float*)b)[i];
}

// one state update: out = (Xhi+Xlo)@M^T + u@B^T (fp32 arm adds lo-matrix terms)
template <int DT>
__device__ __forceinline__ void step_state(const short8& Xhi, const short8& Xlo,
                                           const short8& uhi, const short8& ulo,
                                           const short* Mhi, const short* Mlo,
                                           const short* Bhi, const short* Blo,
                                           f32x4* out, int lane) {
#pragma unroll
  for (int h = 0; h < 2; ++h) {
    const f32x4 z4 = {0.f, 0.f, 0.f, 0.f};
    short8 bA = ldfrag32(Mhi, lane, h * 16);
    f32x4 ax = MFMA16(Xhi, bA, z4);
    ax = MFMA16(Xlo, bA, ax);
    short8 bB = ldfrag16(Bhi, lane, h * 16);
    ax = MFMA16(uhi, bB, ax);
    if constexpr (DT) {
      short8 bAl = ldfrag32(Mlo, lane, h * 16);
      ax = MFMA16(Xhi, bAl, ax);
      ax = MFMA16(ulo, bB, ax);
      short8 bBl = ldfrag16(Blo, lane, h * 16);
      ax = MFMA16(uhi, bBl, ax);
    }
    out[h] = ax;
  }
}

// ---------------- dtype detector ----------------
__global__ void k_detect(const unsigned short* __restrict__ U16, int* __restrict__ flag) {
  if (threadIdx.x == 0) {
    int bad = 0;
    for (int i = 0; i < 512; ++i) {
      int e = (U16[i] >> 7) & 0xFF;
      bad += ((e > 134) || (e < 96 && e != 0)) ? 1 : 0;
    }
    *flag = (bad > 48) ? 1 : 0;
  }
}

// ---------------- K1: chunk-local scans from zero (+ identity tile -> P^T) ----------
template <int DT>
__global__ __launch_bounds__(256) void k1_scan(
    const int* __restrict__ flagp, const void* __restrict__ U,
    const void* __restrict__ Am, const void* __restrict__ Bm,
    const void* __restrict__ Em, const void* __restrict__ Fm,
    float* __restrict__ Sc, float* __restrict__ Sa) {
  if (*flagp != DT) return;
  const int ch = blockIdx.x, tile = blockIdx.y;
  const bool ident = (tile == 64);
  const int tid = threadIdx.x, lane = tid & 63, w = tid >> 6;
  const int s = ch * CHS;

  __shared__ __align__(16) short mA[2][2][1280];
  __shared__ __align__(16) short mB[2][2][768];
  __shared__ __align__(16) short mE[2][2][1280];
  __shared__ __align__(16) short mF[2][2][768];
  __shared__ __align__(16) float T[4][2][16 * TSTR];

  short8 Xhi = {}, Xlo = {}, Zhi = {}, Zlo = {};
  if (ident) {
    const int m = lane & 15, q = lane >> 4;
    short8 id = {};
#pragma unroll
    for (int j = 0; j < 8; ++j) id[j] = ((q * 8 + j) == (w * 16 + m)) ? (short)0x3F80 : (short)0;
    Xhi = id; Zhi = id;
  }

  stage2<DT, 32, 32, 40>(eptr<DT>(Am, (long)s * 1024), mA[0][0], mA[0][1], tid);
  stage2<DT, 32, 16, 24>(eptr<DT>(Bm, (long)s * 512), mB[0][0], mB[0][1], tid);
  stage2<DT, 32, 32, 40>(eptr<DT>(Em, (long)(s + CHS - 1) * 1024), mE[0][0], mE[0][1], tid);
  stage2<DT, 32, 16, 24>(eptr<DT>(Fm, (long)(s + CHS - 1) * 512), mF[0][0], mF[0][1], tid);
  __syncthreads();

  const size_t urow = (size_t)(ident ? 0 : (tile * 64 + w * 16 + (lane & 15))) * 8192;
  const int qq = (lane >> 4) & 1;

  f32x4 aX[2], aZ[2];
  for (int t = 0; t < CHS; ++t) {
    const int kc = s + t, ka = s + CHS - 1 - t, buf = t & 1;
    if (t < CHS - 1) {
      stage2<DT, 32, 32, 40>(eptr<DT>(Am, (long)(kc + 1) * 1024), mA[buf ^ 1][0], mA[buf ^ 1][1], tid);
      stage2<DT, 32, 16, 24>(eptr<DT>(Bm, (long)(kc + 1) * 512), mB[buf ^ 1][0], mB[buf ^ 1][1], tid);
      stage2<DT, 32, 32, 40>(eptr<DT>(Em, (long)(ka - 1) * 1024), mE[buf ^ 1][0], mE[buf ^ 1][1], tid);
      stage2<DT, 32, 16, 24>(eptr<DT>(Fm, (long)(ka - 1) * 512), mF[buf ^ 1][0], mF[buf ^ 1][1], tid);
    }
    short8 uch = {}, ucl = {}, uah = {}, ual = {};
    if (!ident) {
      ldu<DT>(U, urow + kc * 16 + qq * 8, uch, ucl);
      ldu<DT>(U, urow + ka * 16 + qq * 8, uah, ual);
    }
    step_state<DT>(Xhi, Xlo, uch, ucl, mA[buf][0], mA[buf][1], mB[buf][0], mB[buf][1], aX, lane);
    step_state<DT>(Zhi, Zlo, uah, ual, mE[buf][0], mE[buf][1], mF[buf][0], mF[buf][1], aZ, lane);
    twr(aX, T[w][0], lane);
    twr(aZ, T[w][1], lane);
    __syncthreads();
    trd(T[w][0], lane, Xhi, Xlo);
    trd(T[w][1], lane, Zhi, Zlo);
    __syncthreads();
  }

  if (!ident || w < 2) {
    const int grow = tile * 64 + w * 16;
#pragma unroll
    for (int h = 0; h < 2; ++h)
#pragma unroll
      for (int r = 0; r < 4; ++r) {
        const int m = (lane >> 4) * 4 + r, col = h * 16 + (lane & 15);
        const size_t off = ((size_t)ch * SROWS + grow + m) * 32 + col;
        Sc[off] = aX[h][r];
        Sa[off] = aZ[h][r];
      }
  }
}

// ---------------- K2: sequential fp32 combine over chunks ----------------
__global__ __launch_bounds__(256) void k2_comb(float* __restrict__ Sc, float* __restrict__ Sa) {
  const int dir = blockIdx.y;
  const int r = threadIdx.x >> 5, j = threadIdx.x & 31;
  const int row = blockIdx.x * 8 + r;
  float* S = dir ? Sa : Sc;
  __shared__ float P[32][33];
  __shared__ float xs[8][33];
  float x = 0.f;
  for (int it = 0; it < NCH; ++it) {
    const int ch = dir ? (NCH - 1 - it) : it;
    const size_t base = ((size_t)ch * SROWS + row) * 32 + j;
    const float s_local = S[base];
    for (int i = threadIdx.x; i < 1024; i += 256)
      P[i >> 5][i & 31] = S[((size_t)ch * SROWS + BATCH + (i >> 5)) * 32 + (i & 31)];
    xs[r][j] = x;
    __syncthreads();
    S[base] = x;
    float acc = s_local;
#pragma unroll
    for (int m = 0; m < 32; ++m) acc += xs[r][m] * P[m][j];
    x = acc;
    __syncthreads();
  }
}

// ---------------- K3: re-scan with true entry states, produce y ----------------
template <int DT>
__global__ __launch_bounds__(256) void k3_scan(
    const int* __restrict__ flagp, const void* __restrict__ U,
    const void* __restrict__ Am, const void* __restrict__ Bm,
    const void* __restrict__ Cm, const void* __restrict__ Dm,
    const void* __restrict__ Em, const void* __restrict__ Fm,
    const void* __restrict__ Gm, const void* __restrict__ biasv,
    const float* __restrict__ xin, const float* __restrict__ zin,
    void* __restrict__ out) {
  if (*flagp != DT) return;
  const int ch = blockIdx.x, tile = blockIdx.y;
  const int tid = threadIdx.x, lane = tid & 63, w = tid >> 6;
  const int s = ch * CHS;
  __shared__ __align__(16) short sA[2][2][1280];
  __shared__ __align__(16) short sB[2][2][768];
  __shared__ __align__(16) short sC[2][640];
  __shared__ __align__(16) short sD[2][384];
  __shared__ __align__(16) float T[4][16 * TSTR];
  const int cidx = lane & 15, quad = lane >> 4, qq = quad & 1;
  const size_t urow = (size_t)(tile * 64 + w * 16 + cidx) * 8192;

  // ---- causal phase ----
  short8 Xhi = {}, Xlo = {};
  {
    const float* xp = xin + ((size_t)ch * SROWS + tile * 64 + w * 16 + cidx) * 32 + quad * 8;
#pragma unroll
    for (int j = 0; j < 8; ++j) {
      float v = xp[j];
      unsigned short h = bf16u(v);
      Xhi[j] = (short)h;
      Xlo[j] = (short)bf16u(v - bf2f(h));
    }
  }
  stage2<DT, 32, 32, 40>(eptr<DT>(Am, (long)s * 1024), sA[0][0], sA[0][1], tid);
  stage2<DT, 32, 16, 24>(eptr<DT>(Bm, (long)s * 512), sB[0][0], sB[0][1], tid);
  stage1<DT, 16, 32, 40>(eptr<DT>(Cm, (long)s * 512), sC[0], tid);
  stage1<DT, 16, 16, 24>(eptr<DT>(Dm, (long)s * 256), sD[0], tid);
  __syncthreads();

  unsigned ypk[2 * CHS];
  f32x4 aX[2];
#pragma unroll
  for (int t = 0; t < CHS; ++t) {
    const int k = s + t, buf = t & 1;
    if (t < CHS - 1) {
      stage2<DT, 32, 32, 40>(eptr<DT>(Am, (long)(k + 1) * 1024), sA[buf ^ 1][0], sA[buf ^ 1][1], tid);
      stage2<DT, 32, 16, 24>(eptr<DT>(Bm, (long)(k + 1) * 512), sB[buf ^ 1][0], sB[buf ^ 1][1], tid);
      stage1<DT, 16, 32, 40>(eptr<DT>(Cm, (long)(k + 1) * 512), sC[buf ^ 1], tid);
      stage1<DT, 16, 16, 24>(eptr<DT>(Dm, (long)(k + 1) * 256), sD[buf ^ 1], tid);
    }
    short8 uh, ul;
    ldu<DT>(U, urow + k * 16 + qq * 8, uh, ul);
    const f32x4 z4 = {0.f, 0.f, 0.f, 0.f};
    const short8 cf = ldfrag32(sC[buf], lane, 0);
    f32x4 ya = MFMA16(Xhi, cf, z4);
    ya = MFMA16(Xlo, cf, ya);
    const short8 df = ldfrag16(sD[buf], lane, 0);
    ya = MFMA16(uh, df, ya);
    if constexpr (DT) ya = MFMA16(ul, df, ya);
    const float bv = ldbias<DT>(biasv, k * 16 + cidx);
    ypk[2 * t] = pk2(ya[0] + bv, ya[1] + bv);
    ypk[2 * t + 1] = pk2(ya[2] + bv, ya[3] + bv);
    step_state<DT>(Xhi, Xlo, uh, ul, sA[buf][0], sA[buf][1], sB[buf][0], sB[buf][1], aX, lane);
    twr(aX, T[w], lane);
    __syncthreads();
    trd(T[w], lane, Xhi, Xlo);
    __syncthreads();
  }

  // ---- anticausal phase ----
  short8 Zhi = {}, Zlo = {};
  {
    const float* zp = zin + ((size_t)ch * SROWS + tile * 64 + w * 16 + cidx) * 32 + quad * 8;
#pragma unroll
    for (int j = 0; j < 8; ++j) {
      float v = zp[j];
      unsigned short h = bf16u(v);
      Zhi[j] = (short)h;
      Zlo[j] = (short)bf16u(v - bf2f(h));
    }
  }
  stage2<DT, 32, 32, 40>(eptr<DT>(Em, (long)(s + CHS - 1) * 1024), sA[0][0], sA[0][1], tid);
  stage2<DT, 32, 16, 24>(eptr<DT>(Fm, (long)(s + CHS - 1) * 512), sB[0][0], sB[0][1], tid);
  stage1<DT, 16, 32, 40>(eptr<DT>(Gm, (long)(s + CHS - 1) * 512), sC[0], tid);
  __syncthreads();

  f32x4 aZ[2];
#pragma unroll
  for (int t = 0; t < CHS; ++t) {
    const int k = s + CHS - 1 - t, buf = t & 1;
    if (t < CHS - 1) {
      stage2<DT, 32, 32, 40>(eptr<DT>(Em, (long)(k - 1) * 1024), sA[buf ^ 1][0], sA[buf ^ 1][1], tid);
      stage2<DT, 32, 16, 24>(eptr<DT>(Fm, (long)(k - 1) * 512), sB[buf ^ 1][0], sB[buf ^ 1][1], tid);
      stage1<DT, 16, 32, 40>(eptr<DT>(Gm, (long)(k - 1) * 512), sC[buf ^ 1], tid);
    }
    short8 uh, ul;
    ldu<DT>(U, urow + k * 16 + qq * 8, uh, ul);
    const f32x4 z4 = {0.f, 0.f, 0.f, 0.f};
    const short8 gf = ldfrag32(sC[buf], lane, 0);
    f32x4 ya = MFMA16(Zhi, gf, z4);
    ya = MFMA16(Zlo, gf, ya);
    {
      const int yi = 2 * (CHS - 1 - t);
      const int orow = tile * 64 + w * 16 + quad * 4;
      const size_t obase = (size_t)orow * 8192 + k * 16 + cidx;
      const float c0 = bf2f((unsigned short)(ypk[yi] & 0xffffu));
      const float c1 = bf2f((unsigned short)(ypk[yi] >> 16));
      const float c2 = bf2f((unsigned short)(ypk[yi + 1] & 0xffffu));
      const float c3 = bf2f((unsigned short)(ypk[yi + 1] >> 16));
      if constexpr (DT == 0) {
        short* o = (short*)out;
        o[obase + 0 * 8192] = (short)bf16u(c0 + ya[0]);
        o[obase + 1 * 8192] = (short)bf16u(c1 + ya[1]);
        o[obase + 2 * 8192] = (short)bf16u(c2 + ya[2]);
        o[obase + 3 * 8192] = (short)bf16u(c3 + ya[3]);
      } else {
        float* o = (float*)out;
        o[obase + 0 * 8192] = c0 + ya[0];
        o[obase + 1 * 8192] = c1 + ya[1];
        o[obase + 2 * 8192] = c2 + ya[2];
        o[obase + 3 * 8192] = c3 + ya[3];
      }
    }
    step_state<DT>(Zhi, Zlo, uh, ul, sA[buf][0], sA[buf][1], sB[buf][0], sB[buf][1], aZ, lane);
    twr(aZ, T[w], lane);
    __syncthreads();
    trd(T[w], lane, Zhi, Zlo);
    __syncthreads();
  }
}

extern "C" void kernel_launch(void* const* d_in, const int* in_sizes, int n_in,
                              void* d_out, int out_size, void* d_ws, size_t ws_size,
                              hipStream_t stream) {
  (void)in_sizes; (void)n_in; (void)out_size; (void)ws_size;
  const void* U = d_in[0];
  const void* A = d_in[1];
  const void* B = d_in[2];
  const void* C = d_in[3];
  const void* D = d_in[4];
  const void* E = d_in[5];
  const void* F = d_in[6];
  const void* G = d_in[7];
  const void* bias = d_in[8];

  int* flag = (int*)d_ws;
  float* Sc = (float*)((char*)d_ws + 1024);
  float* Sa = Sc + (size_t)NCH * SROWS * 32;

  k_detect<<<1, 64, 0, stream>>>((const unsigned short*)U, flag);
  k1_scan<0><<<dim3(NCH, 65), 256, 0, stream>>>(flag, U, A, B, E, F, Sc, Sa);
  k1_scan<1><<<dim3(NCH, 65), 256, 0, stream>>>(flag, U, A, B, E, F, Sc, Sa);
  k2_comb<<<dim3(BATCH / 8, 2), 256, 0, stream>>>(Sc, Sa);
  k3_scan<0><<<dim3(NCH, 64), 256, 0, stream>>>(flag, U, A, B, C, D, E, F, G, bias, Sc, Sa, d_out);
  k3_scan<1><<<dim3(NCH, 64), 256, 0, stream>>>(flag, U, A, B, C, D, E, F, G, bias, Sc, Sa, d_out);
}